// Round 4
// baseline (349.383 us; speedup 1.0000x reference)
//
#include <hip/hip_runtime.h>
#include <math.h>
#include <stdint.h>

#define D 128
#define EPS 1e-6f
typedef unsigned short u16;

// ---------------------------------------------------------------------------
// state layout (floats), 16B-aligned base:
//   st[0..127]   : q
//   st[128..255] : q_plus
//   st[256..383] : hop accumulator (device atomicAdd targets)
//   st[384]      : ||q||   st[385] : ||q_plus||   st[386] : sum-of-exp
// Rules: no device fences after bulk writes (r6); no global atomic scatters
// (r8); TCC-MISS gather rate ~3.5-3.8 TB/s (r9/r15); reducer grids <= 1024
// blocks (r10); 1-block serial gathers are latency traps (r11); grid.sync >>
// launch gap (r14, 972us disaster).
// r15: round-2 kvp_k showed FETCH=233MB for a 12.8MB table — random 256B
// gathers thrash the 4MiB/XCD L2 (65% hit). Fix: slice-outer gather — 64B of
// each row per pass = 3.2MB/slice footprint (64B lines) = L2-resident AND
// contiguous. Ids preloaded in regs across all 4 slices; knorm in regs; vb
// slice-major; persona hop in spare block.
// r16: round-3 bench died (container infra, no counters). Re-submit with the
// risky bf16-candidate change REVERTED (absmax sat at 2^-10, likely flush
// against tolerance); candidates stay fp32 with finish-hop fused per-block.
// ---------------------------------------------------------------------------

__device__ __forceinline__ float wave_sum(float v) {
#pragma unroll
    for (int off = 32; off > 0; off >>= 1) v += __shfl_xor(v, off, 64);
    return v;
}
__device__ __forceinline__ float halfwave_sum(float v) {
#pragma unroll
    for (int off = 16; off > 0; off >>= 1) v += __shfl_xor(v, off, 32);
    return v;
}
__device__ __forceinline__ float quarter_sum(float v) {
#pragma unroll
    for (int off = 8; off > 0; off >>= 1) v += __shfl_xor(v, off, 16);
    return v;
}

__device__ __forceinline__ float bf2f(u16 h) {
    union { unsigned u; float f; } x;
    x.u = ((unsigned)h) << 16;
    return x.f;
}
__device__ __forceinline__ float bflo(unsigned u) { return bf2f((u16)(u & 0xffff)); }
__device__ __forceinline__ float bfhi(unsigned u) { return bf2f((u16)(u >> 16)); }
__device__ __forceinline__ u16 f2bf(float f) {  // round-to-nearest-even
    union { float f; unsigned u; } x;
    x.f = f;
    unsigned u = x.u;
    return (u16)((u + 0x7fff + ((u >> 16) & 1)) >> 16);
}
__device__ __forceinline__ unsigned pack2(float a, float b) {
    return (unsigned)f2bf(a) | ((unsigned)f2bf(b) << 16);
}

// ===========================================================================
// prep_k: blocks [0,nbA) convert semb fp32 -> bf16 ROW-MAJOR (coalesced both
// sides); last 3 blocks do the small encodes (persona rows + q).
// ===========================================================================
__global__ void prep_k(const float* __restrict__ semb, u16* __restrict__ tbl,
                       int V, const int* __restrict__ pers, int NP,
                       const int* __restrict__ xs, int LQ,
                       float* __restrict__ enc_pers, float* __restrict__ pnorms,
                       float* __restrict__ st, int nbA) {
    const int tid = threadIdx.x;
    const int bid = blockIdx.x;
    if (bid < nbA) {
        const int n = V * 64;  // channel-pairs
        const int stride = nbA * 256;
        for (int i = bid * 256 + tid; i < n; i += stride) {
            const int v = i >> 6;
            const int c2 = i & 63;
            const float2 ab = *(const float2*)(semb + (long)v * D + 2 * c2);
            *(unsigned*)(tbl + (long)v * D + 2 * c2) = pack2(ab.x, ab.y);
        }
    } else {
        const int lane = tid & 63;
        const int half = lane >> 5;
        const int hl = lane & 31;
        const int w0 = (bid - nbA) * 4 + (tid >> 6);
        const int npr = NP + 1;  // +1 virtual q row
        const int npairs = (npr + 1) >> 1;
        for (int w = w0; w < npairs; w += 12) {
            const int row = 2 * w + half;
            const bool valid = row < npr;
            const int rowc = valid ? row : NP;
            const bool isq = (rowc == NP);
            const int* ids = isq ? xs : (pers + (long)rowc * 20);
            const int L = isq ? LQ : 20;
            int myid = 0;
            if (hl < L) myid = ids[hl];
            float4 acc = {0.f, 0.f, 0.f, 0.f};
            for (int t = 0; t < L; ++t) {
                const int idx = __shfl(myid, (half << 5) + t, 64);
                const float4 e = *(const float4*)(semb + (long)idx * D + 4 * hl);
                acc.x += e.x; acc.y += e.y; acc.z += e.z; acc.w += e.w;
            }
            if (valid) {
                float* outp = isq ? st : (enc_pers + (long)rowc * D);
                *(float4*)(outp + 4 * hl) = acc;
                float sq = acc.x * acc.x + acc.y * acc.y + acc.z * acc.z + acc.w * acc.w;
                sq = halfwave_sum(sq);
                if (hl == 0) {
                    if (isq) st[384] = sqrtf(sq);
                    else pnorms[rowc] = sqrtf(sq);
                }
            }
        }
    }
}

// ===========================================================================
// persona hop device fn (runs on spare block of kv_all, hidden under gather)
// ===========================================================================
__device__ void persona_dev(const float* __restrict__ pers_rows,
                            const float* __restrict__ pnorms,
                            const float* __restrict__ W, float* __restrict__ st,
                            int NP, float* smem, int tid) {
    float* qsh = smem;          // 128
    float* qh = smem + 128;     // 128
    float* att = smem + 256;    // 64
    float* red = smem + 320;    // 2
    if (tid < D) qsh[tid] = st[tid];
    __syncthreads();
    if (tid < NP) {
        float dot = 0.f;
        const float* pr = pers_rows + (long)tid * D;
        for (int d2 = 0; d2 < D; ++d2) dot += pr[d2] * qsh[d2];
        att[tid] = dot / fmaxf(pnorms[tid] * st[384], EPS);
    }
    __syncthreads();
    if (tid == 0) {
        float m = -1e30f;
        for (int p = 0; p < NP; ++p) m = fmaxf(m, att[p]);
        float s = 0.f;
        for (int p = 0; p < NP; ++p) { att[p] = __expf(att[p] - m); s += att[p]; }
        float inv = 1.f / s;
        for (int p = 0; p < NP; ++p) att[p] *= inv;
    }
    __syncthreads();
    if (tid < D) {
        float h = 0.f;
        for (int p = 0; p < NP; ++p) h += att[p] * pers_rows[(long)p * D + tid];
        qh[tid] = qsh[tid] + h;
    }
    __syncthreads();
    float qp = 0.f;
    if (tid < D) {
        for (int d2 = 0; d2 < D; ++d2) qp += W[(long)tid * D + d2] * qh[d2];
        st[128 + tid] = qp;
    }
    float sq = wave_sum(qp * qp);
    if ((tid & 63) == 0 && tid < 128) red[tid >> 6] = sq;
    __syncthreads();
    if (tid == 0) st[385] = sqrtf(red[0] + red[1]);
    if (tid < D) st[256 + tid] = 0.f;
    if (tid == 0) st[386] = 0.f;
}

// ===========================================================================
// kv_all: slice-outer KV encode. Quarter-wave (16 lanes) owns a row; per
// slice s, lane ql reads uint (ch 32s+2ql, +1) = 64B contiguous per row.
// Slice cache footprint = V*64B = 3.2MB -> L2-resident per XCD. Ids
// preloaded ONCE into regs (reused all 4 slices); knorm partial lane-local
// in regs across slices; vb written slice-major. Last block: persona hop.
// ===========================================================================
__device__ __forceinline__ float kv_slice_group(
    const u16* __restrict__ tbl, int s, int q, int ql, int kA, int kB,
    int vA, int vB, u16* __restrict__ vb, int N, int g) {
    float k0 = 0.f, k1 = 0.f, v0 = 0.f, v1 = 0.f;
#pragma unroll
    for (int t = 0; t < 20; ++t) {
        const int j = 20 * q + t;
        const int jb = j - 64;
        const int ka = __shfl(kA, j & 63, 64);
        const int kb = __shfl(kB, jb < 0 ? 0 : jb, 64);
        const int va = __shfl(vA, j & 63, 64);
        const int vbr = __shfl(vB, jb < 0 ? 0 : jb, 64);
        const int kj = (j < 64) ? ka : kb;
        const int vj = (j < 64) ? va : vbr;
        const unsigned ke = *(const unsigned*)(tbl + (long)kj * D + 32 * s + 2 * ql);
        const unsigned ve = *(const unsigned*)(tbl + (long)vj * D + 32 * s + 2 * ql);
        k0 += bflo(ke); k1 += bfhi(ke);
        v0 += bflo(ve); v1 += bfhi(ve);
    }
    const int row = 4 * g + q;
    *(unsigned*)(vb + ((long)s * N + row) * 32 + 2 * ql) = pack2(v0, v1);
    return k0 * k0 + k1 * k1;
}

__global__ void kv_all(const u16* __restrict__ tbl, const int* __restrict__ kids,
                       const int* __restrict__ vids, int N,
                       u16* __restrict__ vb, float* __restrict__ knorms,
                       const float* __restrict__ enc_pers,
                       const float* __restrict__ pnorms,
                       const float* __restrict__ RW, float* __restrict__ st,
                       int NP) {
    __shared__ float smem[336];
    const int tid = threadIdx.x;
    const int bid = blockIdx.x;
    const int nbKV = gridDim.x - 1;
    if (bid == nbKV) {  // spare block: persona hop (hidden under gather)
        persona_dev(enc_pers, pnorms, RW, st, NP, smem, tid);
        return;
    }
    const int lane = tid & 63;
    const int q = lane >> 4;
    const int ql = lane & 15;
    const int w = bid * 4 + (tid >> 6);
    const int nwaves = nbKV * 4;
    const int ngroup = N >> 2;
    const int g0 = w;
    const int g1 = w + nwaves;
    int kA0 = 0, kB0 = 0, vA0 = 0, vB0 = 0;
    int kA1 = 0, kB1 = 0, vA1 = 0, vB1 = 0;
    if (g0 < ngroup) {
        const long ib = (long)g0 * 80;
        kA0 = kids[ib + lane]; vA0 = vids[ib + lane];
        if (lane < 16) { kB0 = kids[ib + 64 + lane]; vB0 = vids[ib + 64 + lane]; }
    }
    if (g1 < ngroup) {
        const long ib = (long)g1 * 80;
        kA1 = kids[ib + lane]; vA1 = vids[ib + lane];
        if (lane < 16) { kB1 = kids[ib + 64 + lane]; vB1 = vids[ib + 64 + lane]; }
    }
    float sq0 = 0.f, sq1 = 0.f;
#pragma unroll
    for (int s = 0; s < 4; ++s) {  // slice-outer: 3.2MB footprint per slice
        if (g0 < ngroup) sq0 += kv_slice_group(tbl, s, q, ql, kA0, kB0, vA0, vB0, vb, N, g0);
        if (g1 < ngroup) sq1 += kv_slice_group(tbl, s, q, ql, kA1, kB1, vA1, vB1, vb, N, g1);
    }
    if (g0 < ngroup) {
        const float sq = quarter_sum(sq0);
        if (ql == 0) knorms[4 * g0 + q] = sqrtf(sq);
    }
    if (g1 < ngroup) {
        const float sq = quarter_sum(sq1);
        if (ql == 0) knorms[4 * g1 + q] = sqrtf(sq);
    }
}

// ===========================================================================
// a2_k: s[v] = T16[v] . q_plus. Row-major: 64 lanes x uint = 256B contiguous.
// ===========================================================================
__global__ void a2_k(const u16* __restrict__ tbl, const float* __restrict__ st,
                     float* __restrict__ s, int V) {
    const int lane = threadIdx.x & 63;
    const float2 qp2 = *(const float2*)(st + 128 + 2 * lane);
    const int gw = (int)((blockIdx.x * blockDim.x + threadIdx.x) >> 6);
    const int nw = (int)((gridDim.x * blockDim.x) >> 6);
    for (int v = gw; v < V; v += nw) {
        const unsigned u = *(const unsigned*)(tbl + (long)v * D + 2 * lane);
        float d = bflo(u) * qp2.x + bfhi(u) * qp2.y;
        d = wave_sum(d);
        if (lane == 0) s[v] = d;
    }
}

// ===========================================================================
// attcv_k: fused b2e + cv. Half-wave per row: 20-lane sv gather -> dot ->
// e = exp(cos) in-register -> accumulate e * vb_row (slice-major ushort4).
// GRID <= 1024 BLOCKS (r10: ends in st atomics).
// ===========================================================================
__global__ void attcv_k(const float* __restrict__ sv, const int* __restrict__ kids,
                        const float* __restrict__ knorms, const u16* __restrict__ vb,
                        float* __restrict__ st, int N) {
    __shared__ float smem[129];
    const int tid = threadIdx.x;
    const int lane = tid & 63;
    const int half = lane >> 5;
    const int hl = lane & 31;
    const int s4 = hl >> 3;
    const int w8 = hl & 7;
    const float qpn = st[385];
    const int ghw = (int)((blockIdx.x * blockDim.x + tid) >> 5);
    const int nhw = (int)((gridDim.x * blockDim.x) >> 5);
    float a0 = 0.f, a1 = 0.f, a2 = 0.f, a3 = 0.f;
    float esum = 0.f;
    for (int i = ghw; i < N; i += nhw) {
        float partial = 0.f;
        if (hl < 20) partial = sv[kids[(long)i * 20 + hl]];
        const float dot = halfwave_sum(partial);
        const float c = dot / fmaxf(knorms[i] * qpn, EPS);
        const float e = __expf(c);
        const ushort4 vh = *(const ushort4*)(vb + ((long)s4 * N + i) * 32 + 4 * w8);
        a0 += e * bf2f(vh.x);
        a1 += e * bf2f(vh.y);
        a2 += e * bf2f(vh.z);
        a3 += e * bf2f(vh.w);
        if (hl == 0) esum += e;
    }
    a0 += __shfl_xor(a0, 32, 64);
    a1 += __shfl_xor(a1, 32, 64);
    a2 += __shfl_xor(a2, 32, 64);
    a3 += __shfl_xor(a3, 32, 64);
    esum += __shfl_xor(esum, 32, 64);
    if (tid < 129) smem[tid] = 0.f;
    __syncthreads();
    if (half == 0) {
        const int ch = 32 * s4 + 4 * w8;
        atomicAdd(&smem[ch + 0], a0);
        atomicAdd(&smem[ch + 1], a1);
        atomicAdd(&smem[ch + 2], a2);
        atomicAdd(&smem[ch + 3], a3);
        if (hl == 0) atomicAdd(&smem[128], esum);
    }
    __syncthreads();
    if (tid < 128) atomicAdd(&st[256 + tid], smem[tid]);
    if (tid == 128) atomicAdd(&st[386], smem[128]);
}

// ===========================================================================
// mid_hop (1 block, 128 threads) — known-good.
// ===========================================================================
__global__ void mid_hop(const float* __restrict__ W1, const float* __restrict__ W2,
                        const float* __restrict__ pers_rows,
                        const float* __restrict__ pnorms,
                        float* __restrict__ st, int NP) {
    __shared__ float qh[D];
    __shared__ float qsh[D];
    __shared__ float att[64];
    __shared__ float red[2];
    int tid = threadIdx.x;
    float inv = 1.f / st[386];
    qh[tid] = st[128 + tid] + st[256 + tid] * inv;
    __syncthreads();
    float qn = 0.f;
    for (int d2 = 0; d2 < D; ++d2) qn += W1[tid * D + d2] * qh[d2];
    qsh[tid] = qn;
    st[tid] = qn;
    float sq = wave_sum(qn * qn);
    if ((tid & 63) == 0) red[tid >> 6] = sq;
    __syncthreads();
    float qnorm = sqrtf(red[0] + red[1]);
    if (tid == 0) st[384] = qnorm;
    if (tid < NP) {
        float dot = 0.f;
        for (int d2 = 0; d2 < D; ++d2) dot += pers_rows[tid * D + d2] * qsh[d2];
        att[tid] = dot / fmaxf(pnorms[tid] * qnorm, EPS);
    }
    __syncthreads();
    if (tid == 0) {
        float m = -1e30f;
        for (int p = 0; p < NP; ++p) m = fmaxf(m, att[p]);
        float s = 0.f;
        for (int p = 0; p < NP; ++p) { att[p] = __expf(att[p] - m); s += att[p]; }
        float is = 1.f / s;
        for (int p = 0; p < NP; ++p) att[p] *= is;
    }
    __syncthreads();
    float h = 0.f;
    for (int p = 0; p < NP; ++p) h += att[p] * pers_rows[p * D + tid];
    qh[tid] = qsh[tid] + h;
    __syncthreads();
    float qp = 0.f;
    for (int d2 = 0; d2 < D; ++d2) qp += W2[tid * D + d2] * qh[d2];
    st[128 + tid] = qp;
    float sq2 = wave_sum(qp * qp);
    if ((tid & 63) == 0) red[tid >> 6] = sq2;
    __syncthreads();
    if (tid == 0) st[385] = sqrtf(red[0] + red[1]);
    st[256 + tid] = 0.f;
    if (tid == 0) st[386] = 0.f;
}

// ===========================================================================
// k5f: finish-hop per-block in smem (removes a launch; W2 is L2-broadcast),
// then fp32 candidate gather + cosine (proven precision).
// ===========================================================================
__global__ void k5f(const float* __restrict__ W2, const float* __restrict__ cemb,
                    const int* __restrict__ cands, int NC,
                    const float* __restrict__ st, float* __restrict__ out) {
    __shared__ float qv[D];
    __shared__ float qhsh[D];
    __shared__ float red[2];
    __shared__ float qns;
    const int tid = threadIdx.x;
    // ---- finish-hop prologue (every block; deterministic identical result)
    const float inv = 1.f / st[386];
    if (tid < D) qhsh[tid] = st[128 + tid] + st[256 + tid] * inv;
    __syncthreads();
    float qn = 0.f;
    if (tid < D) {
        for (int d2 = 0; d2 < D; ++d2) qn += W2[(long)tid * D + d2] * qhsh[d2];
        qv[tid] = qn;
    }
    float sq = wave_sum(qn * qn);
    if ((tid & 63) == 0 && tid < 128) red[tid >> 6] = sq;
    __syncthreads();
    if (tid == 0) qns = sqrtf(red[0] + red[1]);
    __syncthreads();
    // ---- candidate gather + cosine
    const int lane = tid & 63;
    const int half = lane >> 5;
    const int hl = lane & 31;
    const int gw = (int)((blockIdx.x * blockDim.x + tid) >> 6);
    const int nw = (int)((gridDim.x * blockDim.x) >> 6);
    const float4 q4 = *(const float4*)(qv + 4 * hl);
    const float qnf = qns;
    const int npair = (NC + 1) >> 1;
    for (int p = gw; p < npair; p += nw) {
        const int row = 2 * p + half;
        const bool valid = row < NC;
        const int rowc = valid ? row : (NC - 1);
        int myid = 0;
        if (hl < 20) myid = cands[(long)rowc * 20 + hl];
        float4 acc = {0.f, 0.f, 0.f, 0.f};
#pragma unroll
        for (int t = 0; t < 20; ++t) {
            const int idx = __shfl(myid, (half << 5) + t, 64);
            const float4 e = *(const float4*)(cemb + (long)idx * D + 4 * hl);
            acc.x += e.x; acc.y += e.y; acc.z += e.z; acc.w += e.w;
        }
        float dot = halfwave_sum(acc.x * q4.x + acc.y * q4.y +
                                 acc.z * q4.z + acc.w * q4.w);
        float nsq = halfwave_sum(acc.x * acc.x + acc.y * acc.y +
                                 acc.z * acc.z + acc.w * acc.w);
        if (valid && hl == 0) out[row] = dot / fmaxf(sqrtf(nsq) * qnf, EPS);
    }
}

// ===========================================================================
// Fallback path kernels (no/undersized workspace): fp32 on-the-fly.
// ===========================================================================
__global__ void encode_small_p(const float* __restrict__ emb,
                               const int* __restrict__ pers, int NP, int LP,
                               const int* __restrict__ xs, int LQ,
                               float* __restrict__ pers_rows,
                               float* __restrict__ pnorms,
                               float* __restrict__ st) {
    const int lane = threadIdx.x & 63;
    const int half = lane >> 5;
    const int hl = lane & 31;
    int gw = (int)((blockIdx.x * blockDim.x + threadIdx.x) >> 6);
    int nw = (int)((gridDim.x * blockDim.x) >> 6);
    const int npr = NP + 1;
    const int npairs = (npr + 1) >> 1;
    for (int p = gw; p < npairs; p += nw) {
        const int row = 2 * p + half;
        const bool valid = row < npr;
        const int rowc = valid ? row : NP;
        const bool isq = (rowc == NP);
        const int* ids = isq ? xs : (pers + (long)rowc * LP);
        const int L = isq ? LQ : LP;
        int myid = 0;
        if (hl < L) myid = ids[hl];
        float4 acc = {0.f, 0.f, 0.f, 0.f};
        for (int t = 0; t < L; ++t) {
            const int idx = __shfl(myid, (half << 5) + t, 64);
            const float4 e = *(const float4*)(emb + (long)idx * D + 4 * hl);
            acc.x += e.x; acc.y += e.y; acc.z += e.z; acc.w += e.w;
        }
        if (valid) {
            float* outp = isq ? st : (pers_rows + (long)rowc * D);
            *(float4*)(outp + 4 * hl) = acc;
            float sq = acc.x * acc.x + acc.y * acc.y + acc.z * acc.z + acc.w * acc.w;
            sq = halfwave_sum(sq);
            if (hl == 0) {
                if (isq) st[384] = sqrtf(sq);
                else pnorms[rowc] = sqrtf(sq);
            }
        }
    }
}

__global__ void persona_hop(const float* __restrict__ pers_rows,
                            const float* __restrict__ pnorms,
                            const float* __restrict__ W,
                            float* __restrict__ st, int NP) {
    __shared__ float smem[336];
    persona_dev(pers_rows, pnorms, W, st, NP, smem, (int)threadIdx.x);
}

__global__ void finish_hop(const float* __restrict__ W, float* __restrict__ st) {
    __shared__ float qh[D];
    __shared__ float red[2];
    int tid = threadIdx.x;
    float inv = 1.f / st[386];
    qh[tid] = st[128 + tid] + st[256 + tid] * inv;
    __syncthreads();
    float qn = 0.f;
    for (int d2 = 0; d2 < D; ++d2) qn += W[tid * D + d2] * qh[d2];
    st[tid] = qn;
    float sq = wave_sum(qn * qn);
    if ((tid & 63) == 0) red[tid >> 6] = sq;
    __syncthreads();
    if (tid == 0) st[384] = sqrtf(red[0] + red[1]);
}

__global__ void k5_final(const float* __restrict__ cemb,
                         const int* __restrict__ cands, int NC,
                         const float* __restrict__ st, float* __restrict__ out) {
    const int lane = threadIdx.x & 63;
    const int half = lane >> 5;
    const int hl = lane & 31;
    const int gw = (int)((blockIdx.x * blockDim.x + threadIdx.x) >> 6);
    const int nw = (int)((gridDim.x * blockDim.x) >> 6);
    const float4 q4 = *(const float4*)(st + 4 * hl);
    const float qn = st[384];
    const int npair = (NC + 1) >> 1;
    for (int p = gw; p < npair; p += nw) {
        const int row = 2 * p + half;
        const bool valid = row < NC;
        const int rowc = valid ? row : (NC - 1);
        int myid = 0;
        if (hl < 20) myid = cands[(long)rowc * 20 + hl];
        float4 acc = {0.f, 0.f, 0.f, 0.f};
#pragma unroll
        for (int t = 0; t < 20; ++t) {
            const int idx = __shfl(myid, (half << 5) + t, 64);
            const float4 e = *(const float4*)(cemb + (long)idx * D + 4 * hl);
            acc.x += e.x; acc.y += e.y; acc.z += e.z; acc.w += e.w;
        }
        float dot = halfwave_sum(acc.x * q4.x + acc.y * q4.y +
                                 acc.z * q4.z + acc.w * q4.w);
        float nsq = halfwave_sum(acc.x * acc.x + acc.y * acc.y +
                                 acc.z * acc.z + acc.w * acc.w);
        if (valid && hl == 0) out[row] = dot / fmaxf(sqrtf(nsq) * qn, EPS);
    }
}

__global__ void big_att_rc(const float* __restrict__ emb,
                           const int* __restrict__ kids,
                           const int* __restrict__ vids,
                           float* __restrict__ st, int N) {
    __shared__ float s[129];
    const int tid = threadIdx.x;
    const int lane = tid & 63;
    const int half = lane >> 5;
    const int hl = lane & 31;
    const int gw = (int)((blockIdx.x * blockDim.x + tid) >> 6);
    const int nw = (int)((gridDim.x * blockDim.x) >> 6);
    const float4 qp = *(const float4*)(st + 128 + 4 * hl);
    const float qpn = st[385];
    float4 hacc = {0.f, 0.f, 0.f, 0.f};
    float esum = 0.f;
    const int npair = (N + 1) >> 1;
    for (int p = gw; p < npair; p += nw) {
        const int row = 2 * p + half;
        const bool valid = row < N;
        const int rowc = valid ? row : (N - 1);
        int kid = 0, vid = 0;
        if (hl < 20) {
            kid = kids[(long)rowc * 20 + hl];
            vid = vids[(long)rowc * 20 + hl];
        }
        float4 ka = {0.f, 0.f, 0.f, 0.f}, va = {0.f, 0.f, 0.f, 0.f};
#pragma unroll
        for (int t = 0; t < 20; ++t) {
            const int ki = __shfl(kid, (half << 5) + t, 64);
            const int vi = __shfl(vid, (half << 5) + t, 64);
            const float4 ke = *(const float4*)(emb + (long)ki * D + 4 * hl);
            const float4 ve = *(const float4*)(emb + (long)vi * D + 4 * hl);
            ka.x += ke.x; ka.y += ke.y; ka.z += ke.z; ka.w += ke.w;
            va.x += ve.x; va.y += ve.y; va.z += ve.z; va.w += ve.w;
        }
        float nsq = halfwave_sum(ka.x * ka.x + ka.y * ka.y + ka.z * ka.z + ka.w * ka.w);
        float dot = halfwave_sum(ka.x * qp.x + ka.y * qp.y + ka.z * qp.z + ka.w * qp.w);
        const float c = dot / fmaxf(sqrtf(nsq) * qpn, EPS);
        float e = __expf(c);
        if (!valid) e = 0.f;
        hacc.x += e * va.x; hacc.y += e * va.y;
        hacc.z += e * va.z; hacc.w += e * va.w;
        if (hl == 0) esum += e;
    }
    hacc.x += __shfl_xor(hacc.x, 32, 64);
    hacc.y += __shfl_xor(hacc.y, 32, 64);
    hacc.z += __shfl_xor(hacc.z, 32, 64);
    hacc.w += __shfl_xor(hacc.w, 32, 64);
    esum += __shfl_xor(esum, 32, 64);
    if (tid < 129) s[tid] = 0.f;
    __syncthreads();
    if (half == 0) {
        atomicAdd(&s[4 * hl + 0], hacc.x);
        atomicAdd(&s[4 * hl + 1], hacc.y);
        atomicAdd(&s[4 * hl + 2], hacc.z);
        atomicAdd(&s[4 * hl + 3], hacc.w);
        if (hl == 0) atomicAdd(&s[128], esum);
    }
    __syncthreads();
    if (tid < 128) atomicAdd(&st[256 + tid], s[tid]);
    if (tid == 128) atomicAdd(&st[386], s[128]);
}

static inline size_t align16(size_t b) { return (b + 15) & ~(size_t)15; }

extern "C" void kernel_launch(void* const* d_in, const int* in_sizes, int n_in,
                              void* d_out, int out_size, void* d_ws, size_t ws_size,
                              hipStream_t stream) {
    const int* xs = (const int*)d_in[0];
    const int* cands = (const int*)d_in[1];
    const int* pers = (const int*)d_in[2];
    const int* keys = (const int*)d_in[3];
    const int* values = (const int*)d_in[4];
    const float* semb = (const float*)d_in[6];
    const float* cemb = (const float*)d_in[7];
    const float* RW = (const float*)d_in[8];
    const float* R2W = (const float*)d_in[9];
    float* out = (float*)d_out;

    const int L = 20;
    const int LQ = in_sizes[0];
    const int VD = in_sizes[6];         // V*D (elements)
    const int V = VD / D;               // 50000
    const int NMEM = in_sizes[3] / L;   // 65536
    const int NCAND = in_sizes[1] / L;  // 10000
    const int NPERS = in_sizes[2] / L;  // 20

    size_t need = align16((size_t)VD * 2) + align16((size_t)NMEM * D * 2) +
                  align16((size_t)NMEM * 4) + align16((size_t)V * 4) +
                  align16((size_t)NPERS * D * 4) + align16((size_t)NPERS * 4) +
                  512 * 4;
    bool stored = (d_ws != nullptr) && (ws_size >= need) && (NMEM % 4 == 0) &&
                  (NMEM <= 65536) && ((VD & 3) == 0) && (LQ <= 32);

    const int THR = 256;
    char* base = (char*)d_ws;
    u16 *tbl16 = nullptr, *vb = nullptr;
    float *knorms = nullptr, *sv = nullptr;
    if (stored) {
        tbl16 = (u16*)base;  base += align16((size_t)VD * 2);        // row-major
        vb = (u16*)base;     base += align16((size_t)NMEM * D * 2);  // slice-major
        knorms = (float*)base; base += align16((size_t)NMEM * 4);
        sv = (float*)base;   base += align16((size_t)V * 4);
    }
    float* enc_pers = (float*)base; base += align16((size_t)NPERS * D * 4);
    float* pnorms = (float*)base;   base += align16((size_t)NPERS * 4);
    float* st = (float*)base;

    if (stored) {
        const int nbA = 2048;
        // 1. prep: semb -> bf16 row-major || small encodes
        prep_k<<<nbA + 3, THR, 0, stream>>>(semb, tbl16, V, pers, NPERS, xs, LQ,
                                            enc_pers, pnorms, st, nbA);
        // 2. slice-outer KV encode (L2-resident slices) || persona_hop
        kv_all<<<2049, THR, 0, stream>>>(tbl16, keys, values, NMEM, vb, knorms,
                                         enc_pers, pnorms, RW, st, NPERS);
        // 3-4. hop 1
        a2_k<<<2048, THR, 0, stream>>>(tbl16, st, sv, V);
        attcv_k<<<1024, THR, 0, stream>>>(sv, keys, knorms, vb, st, NMEM);  // r10
        // 5. mid hop
        mid_hop<<<1, 128, 0, stream>>>(RW, R2W, enc_pers, pnorms, st, NPERS);
        // 6-7. hop 2
        a2_k<<<2048, THR, 0, stream>>>(tbl16, st, sv, V);
        attcv_k<<<1024, THR, 0, stream>>>(sv, keys, knorms, vb, st, NMEM);  // r10
        // 8. finish-hop (per-block) + fp32 candidate gather
        int nblk5 = (((NCAND + 1) / 2) + 3) / 4;
        k5f<<<nblk5, THR, 0, stream>>>(R2W, cemb, cands, NCAND, st, out);
        (void)n_in; (void)out_size;
        return;
    }

    // -------- fallback: fp32 on-the-fly gather --------
    {
        int npairs = (NPERS + 2) / 2;
        int blocks = (npairs + 3) / 4;
        encode_small_p<<<blocks, THR, 0, stream>>>(semb, pers, NPERS, L, xs,
                                                   LQ, enc_pers, pnorms, st);
    }
    persona_hop<<<1, 128, 0, stream>>>(enc_pers, pnorms, RW, st, NPERS);
    big_att_rc<<<1024, THR, 0, stream>>>(semb, keys, values, st, NMEM);
    mid_hop<<<1, 128, 0, stream>>>(RW, R2W, enc_pers, pnorms, st, NPERS);
    big_att_rc<<<1024, THR, 0, stream>>>(semb, keys, values, st, NMEM);
    finish_hop<<<1, 128, 0, stream>>>(R2W, st);
    int nblk5 = (((NCAND + 1) / 2) + 3) / 4;
    k5_final<<<nblk5, THR, 0, stream>>>(cemb, cands, NCAND, st, out);

    (void)n_in; (void)out_size;
}